// Round 4
// baseline (501.721 us; speedup 1.0000x reference)
//
#include <hip/hip_runtime.h>

#define N_NODES 40000
#define N_EDGES 640000
#define IN_F 128
#define HID_F 256
#define CLS_F 40
#define MB 64   // nodes per block in fused MLP (N_NODES % MB == 0)
#define KC 16   // k-chunk rows of W1 staged in LDS per iteration

// ---------------- small float4 helpers ----------------

__device__ __forceinline__ float4 f4add(float4 a, float4 b) {
    return make_float4(a.x + b.x, a.y + b.y, a.z + b.z, a.w + b.w);
}
__device__ __forceinline__ float4 f4fma(float s, float4 w, float4 a) {
    return make_float4(fmaf(s, w.x, a.x), fmaf(s, w.y, a.y),
                       fmaf(s, w.z, a.z), fmaf(s, w.w, a.w));
}
__device__ __forceinline__ float4 f4scale(float4 v, float s) {
    return make_float4(v.x * s, v.y * s, v.z * s, v.w * s);
}

// ---------------- CSR build ----------------

__global__ void k_count(const int* __restrict__ dst, int* __restrict__ counts) {
    int e = blockIdx.x * blockDim.x + threadIdx.x;
    if (e < N_EDGES) atomicAdd(&counts[dst[e]], 1);
}

__global__ void k_scan1(const int* __restrict__ counts, int* __restrict__ bsum) {
    __shared__ int s[256];
    int i = blockIdx.x * 256 + threadIdx.x;
    s[threadIdx.x] = (i < N_NODES) ? counts[i] : 0;
    __syncthreads();
    for (int off = 128; off > 0; off >>= 1) {
        if (threadIdx.x < off) s[threadIdx.x] += s[threadIdx.x + off];
        __syncthreads();
    }
    if (threadIdx.x == 0) bsum[blockIdx.x] = s[0];
}

__global__ void k_scan2(int* __restrict__ bsum, int nb) {
    if (blockIdx.x == 0 && threadIdx.x == 0) {
        int run = 0;
        for (int b = 0; b < nb; b++) { int t = bsum[b]; bsum[b] = run; run += t; }
    }
}

// scan3 + norm fused: writes rowptr/cursor and norm/norm2
__global__ void k_scan3(const int* __restrict__ counts, const int* __restrict__ bsum,
                        int* __restrict__ rowptr, int* __restrict__ cursor,
                        float* __restrict__ norm, float* __restrict__ norm2) {
    __shared__ int s[256];
    int t = threadIdx.x;
    int i = blockIdx.x * 256 + t;
    int v = (i < N_NODES) ? counts[i] : 0;
    s[t] = v;
    __syncthreads();
    for (int off = 1; off < 256; off <<= 1) {
        int x = (t >= off) ? s[t - off] : 0;
        __syncthreads();
        s[t] += x;
        __syncthreads();
    }
    if (i < N_NODES) {
        int excl = s[t] - v + bsum[blockIdx.x];
        rowptr[i] = excl;
        cursor[i] = excl;
        float r = rsqrtf(fmaxf((float)v, 1.0f));
        norm[i] = r;
        norm2[i] = r * r;
    }
}

__global__ void k_fill(const int* __restrict__ src, const int* __restrict__ dst,
                       int* __restrict__ cursor, int* __restrict__ csr_src) {
    int e = blockIdx.x * blockDim.x + threadIdx.x;
    if (e < N_EDGES) {
        int d = dst[e];
        int p = atomicAdd(&cursor[d], 1);
        csr_src[p] = src[e];
    }
}

// ---------------- pre-scale: g0 = features * norm[node] ----------------

__global__ void k_pre(const float* __restrict__ f, const float* __restrict__ norm,
                      float* __restrict__ g0) {
    int i4 = blockIdx.x * 256 + threadIdx.x;
    if (i4 < N_NODES * (IN_F / 4)) {
        int node = i4 >> 5;                 // IN_F/4 = 32 float4 per row
        float4 v = ((const float4*)f)[i4];
        ((float4*)g0)[i4] = f4scale(v, norm[node]);
    }
}

// ---------------- W2 transpose: W2t[c][j] = W2[j][c] ----------------

__global__ void k_w2t(const float* __restrict__ W2, float* __restrict__ W2t) {
    int idx = blockIdx.x * 256 + threadIdx.x;
    if (idx < CLS_F * HID_F) {
        int c = idx >> 8, j = idx & 255;    // HID_F = 256
        W2t[idx] = W2[j * CLS_F + c];
    }
}

// ---------------- propagation hop (gather, no atomics) ----------------
// out[n][:] = oscale(n) * sum_{s in in-edges(n)} in[s][:]
// 32 lanes per node, float4 per lane. 4-way unroll -> 4 row gathers in flight.

__global__ __launch_bounds__(256) void k_hop(
        const float* __restrict__ gin, float* __restrict__ gout,
        const int* __restrict__ csr_src, const int* __restrict__ rowptr,
        const int* __restrict__ counts, const float* __restrict__ oscale,
        int use_oscale) {
    int gid  = blockIdx.x * 8 + (threadIdx.x >> 5);
    int lane = threadIdx.x & 31;
    if (gid >= N_NODES) return;
    int start = rowptr[gid];
    int cnt   = counts[gid];
    const int* cp = csr_src + start;
    float4 a0 = make_float4(0.f, 0.f, 0.f, 0.f);
    float4 a1 = a0, a2 = a0, a3 = a0;
    int i = 0;
    for (; i + 4 <= cnt; i += 4) {
        int s0 = cp[i], s1 = cp[i + 1], s2 = cp[i + 2], s3 = cp[i + 3];
        float4 v0 = ((const float4*)(gin + (size_t)s0 * IN_F))[lane];
        float4 v1 = ((const float4*)(gin + (size_t)s1 * IN_F))[lane];
        float4 v2 = ((const float4*)(gin + (size_t)s2 * IN_F))[lane];
        float4 v3 = ((const float4*)(gin + (size_t)s3 * IN_F))[lane];
        a0 = f4add(a0, v0);
        a1 = f4add(a1, v1);
        a2 = f4add(a2, v2);
        a3 = f4add(a3, v3);
    }
    for (; i < cnt; i++) {
        int s = cp[i];
        float4 v = ((const float4*)(gin + (size_t)s * IN_F))[lane];
        a0 = f4add(a0, v);
    }
    float4 r = f4add(f4add(a0, a1), f4add(a2, a3));
    if (use_oscale) r = f4scale(r, oscale[gid]);
    ((float4*)(gout + (size_t)gid * IN_F))[lane] = r;
}

// ---------------- fused MLP: (h2*norm) @ W1 + b1 -> relu -> @ W2 + b2 ----------------
// MB=64 nodes/block, 512 threads, LDS-tiled GEMM:
//   As: 64x128 h-tile (32 KB, norm folded in)
//   Bs: 16x256 W1 k-chunk (16 KB), restaged 8x
// Thread tile: 8 nodes x 4 hid cols (hg = t&63 -> float4 col, ng = t>>6 -> 8 nodes).
// All inner-loop reads are LDS: As reads wave-uniform (broadcast, free),
// Bs reads lane-consecutive float4 (2-way, free). Compiler pipelines ds_read
// with fine-grained lgkmcnt (no global-latency exposure -> the v3 failure mode).
// GEMM2: ReLU'd acc -> ts (reuses As space) in 2 halves of 32 nodes; W2t via L1.

__global__ __launch_bounds__(512) void k_mlp(
        const float* __restrict__ h2, const float* __restrict__ norm,
        const float* __restrict__ W1, const float* __restrict__ b1,
        const float* __restrict__ W2t, const float* __restrict__ b2,
        float* __restrict__ out) {
    __shared__ __align__(16) float smem[MB * IN_F + KC * HID_F];  // 48 KB
    float* As = smem;                 // 8192 floats
    float* Bs = smem + MB * IN_F;     // 4096 floats

    int t  = threadIdx.x;
    int n0 = blockIdx.x * MB;
    int hg = t & 63;
    int ng = t >> 6;                  // 0..7, 8 nodes each

    // stage A: 2048 float4, 4 per thread, coalesced; fold trailing norm
    float4* As4 = (float4*)As;
    const float4* h24 = (const float4*)(h2 + (size_t)n0 * IN_F);
    #pragma unroll
    for (int p = 0; p < 4; p++) {
        int i4 = t + p * 512;
        As4[i4] = f4scale(h24[i4], norm[n0 + (i4 >> 5)]);
    }

    float4 acc[8];
    #pragma unroll
    for (int m = 0; m < 8; m++) acc[m] = make_float4(0.f, 0.f, 0.f, 0.f);

    const float4* W14 = (const float4*)W1;
    float4* Bs4 = (float4*)Bs;
    const float4* ap = As4 + (size_t)(ng * 8) * (IN_F / 4);

    for (int c = 0; c < IN_F / KC; c++) {         // 8 chunks
        __syncthreads();                          // Bs free (also covers As stage 1st time)
        #pragma unroll
        for (int p = 0; p < 2; p++) {             // stage B chunk: 1024 float4
            int i4 = t + p * 512;
            Bs4[i4] = W14[(size_t)(c * KC + (i4 >> 6)) * (HID_F / 4) + (i4 & 63)];
        }
        __syncthreads();
        #pragma unroll
        for (int k4 = 0; k4 < KC / 4; k4++) {
            float4 w0 = Bs4[(k4 * 4 + 0) * 64 + hg];
            float4 w1v = Bs4[(k4 * 4 + 1) * 64 + hg];
            float4 w2v = Bs4[(k4 * 4 + 2) * 64 + hg];
            float4 w3v = Bs4[(k4 * 4 + 3) * 64 + hg];
            int kk = c * (KC / 4) + k4;           // global k4 in [0,32)
            #pragma unroll
            for (int m = 0; m < 8; m++) {
                float4 h4 = ap[m * (IN_F / 4) + kk];   // wave-broadcast
                acc[m] = f4fma(h4.x, w0, acc[m]);
                acc[m] = f4fma(h4.y, w1v, acc[m]);
                acc[m] = f4fma(h4.z, w2v, acc[m]);
                acc[m] = f4fma(h4.w, w3v, acc[m]);
            }
        }
    }

    // bias + relu in registers
    float4 bb = ((const float4*)b1)[hg];
    #pragma unroll
    for (int m = 0; m < 8; m++) {
        acc[m].x = fmaxf(acc[m].x + bb.x, 0.f);
        acc[m].y = fmaxf(acc[m].y + bb.y, 0.f);
        acc[m].z = fmaxf(acc[m].z + bb.z, 0.f);
        acc[m].w = fmaxf(acc[m].w + bb.w, 0.f);
    }

    // GEMM2: two halves of 32 nodes; ts reuses As space (32*256 = 8192 floats)
    float4* ts4 = (float4*)As;                    // [32][64] float4
    #pragma unroll
    for (int half = 0; half < 2; half++) {
        __syncthreads();                          // As dead / previous half's reads done
        if ((ng >> 2) == half) {
            int mbase = (ng & 3) * 8;
            #pragma unroll
            for (int m = 0; m < 8; m++)
                ts4[(size_t)(mbase + m) * (HID_F / 4) + hg] = acc[m];
        }
        __syncthreads();
        for (int o = t; o < 32 * CLS_F; o += 512) {
            int m = o / CLS_F, cc = o % CLS_F;
            const float4* tr = ts4 + (size_t)m * (HID_F / 4);
            const float4* wr = (const float4*)(W2t + (size_t)cc * HID_F);
            float s = b2[cc];
            #pragma unroll 8
            for (int j4 = 0; j4 < HID_F / 4; j4++) {
                float4 a = tr[j4];
                float4 w = wr[j4];
                s = fmaf(a.x, w.x, s);
                s = fmaf(a.y, w.y, s);
                s = fmaf(a.z, w.z, s);
                s = fmaf(a.w, w.w, s);
            }
            out[(size_t)(n0 + half * 32 + m) * CLS_F + cc] = s;
        }
    }
}

// ---------------- launch ----------------

extern "C" void kernel_launch(void* const* d_in, const int* in_sizes, int n_in,
                              void* d_out, int out_size, void* d_ws, size_t ws_size,
                              hipStream_t stream) {
    const float* features = (const float*)d_in[0];
    const int*   src      = (const int*)d_in[1];
    const int*   dst      = (const int*)d_in[2];
    const float* W1       = (const float*)d_in[3];
    const float* b1       = (const float*)d_in[4];
    const float* W2       = (const float*)d_in[5];
    const float* b2       = (const float*)d_in[6];
    float*       out      = (float*)d_out;

    char* ws = (char*)d_ws;
    size_t off = 0;
    auto alloc = [&](size_t bytes) -> void* {
        void* p = ws + off;
        off += (bytes + 255) & ~(size_t)255;
        return p;
    };
    int*   counts = (int*)alloc((size_t)N_NODES * 4);
    int*   rowptr = (int*)alloc((size_t)N_NODES * 4);
    int*   cursor = (int*)alloc((size_t)N_NODES * 4);
    int*   bsum   = (int*)alloc(256 * 4);
    float* norm   = (float*)alloc((size_t)N_NODES * 4);
    float* norm2  = (float*)alloc((size_t)N_NODES * 4);
    float* W2t    = (float*)alloc((size_t)CLS_F * HID_F * 4);
    int*   csr    = (int*)alloc((size_t)N_EDGES * 4);
    float* bufA   = (float*)alloc((size_t)N_NODES * IN_F * 4);
    float* bufB   = (float*)alloc((size_t)N_NODES * IN_F * 4);

    hipMemsetAsync(counts, 0, (size_t)N_NODES * 4, stream);

    int nb = (N_NODES + 255) / 256;   // 157
    k_count<<<(N_EDGES + 255) / 256, 256, 0, stream>>>(dst, counts);
    k_scan1<<<nb, 256, 0, stream>>>(counts, bsum);
    k_scan2<<<1, 64, 0, stream>>>(bsum, nb);
    k_scan3<<<nb, 256, 0, stream>>>(counts, bsum, rowptr, cursor, norm, norm2);
    k_fill<<<(N_EDGES + 255) / 256, 256, 0, stream>>>(src, dst, cursor, csr);
    k_w2t<<<(CLS_F * HID_F + 255) / 256, 256, 0, stream>>>(W2, W2t);

    // g0 = features * norm  -> bufA
    k_pre<<<(N_NODES * (IN_F / 4) + 255) / 256, 256, 0, stream>>>(features, norm, bufA);
    // hop1: bufB = norm2[dst] * sum(g0[src])   (pre-scaled for hop2)
    k_hop<<<(N_NODES + 7) / 8, 256, 0, stream>>>(bufA, bufB, csr, rowptr, counts, norm2, 1);
    // hop2: bufA = sum(bufB[src])              (trailing norm folded into MLP)
    k_hop<<<(N_NODES + 7) / 8, 256, 0, stream>>>(bufB, bufA, csr, rowptr, counts, norm2, 0);

    k_mlp<<<N_NODES / MB, 512, 0, stream>>>(bufA, norm, W1, b1, W2t, b2, out);
}

// Round 5
// 379.512 us; speedup vs baseline: 1.3220x; 1.3220x over previous
//
#include <hip/hip_runtime.h>

#define N_NODES 40000
#define N_EDGES 640000
#define IN_F 128
#define HID_F 256
#define CLS_F 40

// ---------------- small float4 helpers ----------------

__device__ __forceinline__ float4 f4add(float4 a, float4 b) {
    return make_float4(a.x + b.x, a.y + b.y, a.z + b.z, a.w + b.w);
}
__device__ __forceinline__ float4 f4scale(float4 v, float s) {
    return make_float4(v.x * s, v.y * s, v.z * s, v.w * s);
}

// ---------------- CSR build ----------------

__global__ void k_count(const int* __restrict__ dst, int* __restrict__ counts) {
    int e = blockIdx.x * blockDim.x + threadIdx.x;
    if (e < N_EDGES) atomicAdd(&counts[dst[e]], 1);
}

__global__ void k_scan1(const int* __restrict__ counts, int* __restrict__ bsum) {
    __shared__ int s[256];
    int i = blockIdx.x * 256 + threadIdx.x;
    s[threadIdx.x] = (i < N_NODES) ? counts[i] : 0;
    __syncthreads();
    for (int off = 128; off > 0; off >>= 1) {
        if (threadIdx.x < off) s[threadIdx.x] += s[threadIdx.x + off];
        __syncthreads();
    }
    if (threadIdx.x == 0) bsum[blockIdx.x] = s[0];
}

__global__ void k_scan2(int* __restrict__ bsum, int nb) {
    if (blockIdx.x == 0 && threadIdx.x == 0) {
        int run = 0;
        for (int b = 0; b < nb; b++) { int t = bsum[b]; bsum[b] = run; run += t; }
    }
}

// scan3 + norm fused: writes rowptr/cursor and norm/norm2
__global__ void k_scan3(const int* __restrict__ counts, const int* __restrict__ bsum,
                        int* __restrict__ rowptr, int* __restrict__ cursor,
                        float* __restrict__ norm, float* __restrict__ norm2) {
    __shared__ int s[256];
    int t = threadIdx.x;
    int i = blockIdx.x * 256 + t;
    int v = (i < N_NODES) ? counts[i] : 0;
    s[t] = v;
    __syncthreads();
    for (int off = 1; off < 256; off <<= 1) {
        int x = (t >= off) ? s[t - off] : 0;
        __syncthreads();
        s[t] += x;
        __syncthreads();
    }
    if (i < N_NODES) {
        int excl = s[t] - v + bsum[blockIdx.x];
        rowptr[i] = excl;
        cursor[i] = excl;
        float r = rsqrtf(fmaxf((float)v, 1.0f));
        norm[i] = r;
        norm2[i] = r * r;
    }
}

__global__ void k_fill(const int* __restrict__ src, const int* __restrict__ dst,
                       int* __restrict__ cursor, int* __restrict__ csr_src) {
    int e = blockIdx.x * blockDim.x + threadIdx.x;
    if (e < N_EDGES) {
        int d = dst[e];
        int p = atomicAdd(&cursor[d], 1);
        csr_src[p] = src[e];
    }
}

// ---------------- pre-scale: g0 = features * norm[node] ----------------

__global__ void k_pre(const float* __restrict__ f, const float* __restrict__ norm,
                      float* __restrict__ g0) {
    int i4 = blockIdx.x * 256 + threadIdx.x;
    if (i4 < N_NODES * (IN_F / 4)) {
        int node = i4 >> 5;                 // IN_F/4 = 32 float4 per row
        float4 v = ((const float4*)f)[i4];
        ((float4*)g0)[i4] = f4scale(v, norm[node]);
    }
}

// ---------------- W1 transpose: W1t[j][k] = W1[k][j] ----------------

__global__ void k_w1t(const float* __restrict__ W1, float* __restrict__ W1t) {
    int idx = blockIdx.x * 256 + threadIdx.x;
    if (idx < HID_F * IN_F) {
        int j = idx >> 7, k = idx & 127;    // IN_F = 128
        W1t[idx] = W1[k * HID_F + j];
    }
}

// ---------------- propagation hop (gather, no atomics) ----------------

__global__ __launch_bounds__(256) void k_hop(
        const float* __restrict__ gin, float* __restrict__ gout,
        const int* __restrict__ csr_src, const int* __restrict__ rowptr,
        const int* __restrict__ counts, const float* __restrict__ oscale,
        int use_oscale) {
    int gid  = blockIdx.x * 8 + (threadIdx.x >> 5);
    int lane = threadIdx.x & 31;
    if (gid >= N_NODES) return;
    int start = rowptr[gid];
    int cnt   = counts[gid];
    const int* cp = csr_src + start;
    float4 a0 = make_float4(0.f, 0.f, 0.f, 0.f);
    float4 a1 = a0, a2 = a0, a3 = a0;
    int i = 0;
    for (; i + 4 <= cnt; i += 4) {
        int s0 = cp[i], s1 = cp[i + 1], s2 = cp[i + 2], s3 = cp[i + 3];
        float4 v0 = ((const float4*)(gin + (size_t)s0 * IN_F))[lane];
        float4 v1 = ((const float4*)(gin + (size_t)s1 * IN_F))[lane];
        float4 v2 = ((const float4*)(gin + (size_t)s2 * IN_F))[lane];
        float4 v3 = ((const float4*)(gin + (size_t)s3 * IN_F))[lane];
        a0 = f4add(a0, v0);
        a1 = f4add(a1, v1);
        a2 = f4add(a2, v2);
        a3 = f4add(a3, v3);
    }
    for (; i < cnt; i++) {
        int s = cp[i];
        float4 v = ((const float4*)(gin + (size_t)s * IN_F))[lane];
        a0 = f4add(a0, v);
    }
    float4 r = f4add(f4add(a0, a1), f4add(a2, a3));
    if (use_oscale) r = f4scale(r, oscale[gid]);
    ((float4*)(gout + (size_t)gid * IN_F))[lane] = r;
}

// ---------------- fused MLP (GEMV-style, scalar-broadcast weights) ----------------
// out[n] = relu((h2[n]*norm[n]) @ W1 + b1) @ W2 + b2
// Block = 256 thr = 4 waves; lane (0..63) = node within block (64 nodes/block,
// 625 blocks); wave index kh = k-quarter (readfirstlane -> provably wave-uniform,
// so ALL weight/bias addresses are uniform -> compiler emits s_load; inner loop
// is pure v_fmac_f32 v,s,v: no vector-memory and no LDS in the hot path).
// Each thread holds h[n][kh*32..+32) in 8 float4 (32 VGPR).
// Per 16-j tile: each wave writes 16 partial dots to LDS (stride-20 rows ->
// b128 ops hit all 32 banks exactly 8x = conflict-free minimum), barrier, every
// wave sums the 4 partials, adds b1, relu, and accumulates GEMM2 for its own
// 10-class quarter with wave-uniform W2 scalars. 10 outputs/thread in VGPRs.

__global__ __launch_bounds__(256) void k_mlp(
        const float* __restrict__ h2, const float* __restrict__ norm,
        const float* __restrict__ W1t, const float* __restrict__ b1,
        const float* __restrict__ W2, const float* __restrict__ b2,
        float* __restrict__ out) {
    __shared__ __align__(16) float ts[4 * 64 * 20];   // 20 KB, [g][lane][16+4pad]
    int t    = threadIdx.x;
    int lane = t & 63;
    int kh   = __builtin_amdgcn_readfirstlane(t >> 6);   // 0..3, wave-uniform
    int n    = blockIdx.x * 64 + lane;

    // stage this node's k-quarter, trailing norm folded in
    float4 h[8];
    const float4* hp = (const float4*)(h2 + (size_t)n * IN_F + kh * 32);
    float nr = norm[n];
    #pragma unroll
    for (int i = 0; i < 8; i++) h[i] = f4scale(hp[i], nr);

    const float* wq = W1t + kh * 32;       // + j*IN_F, uniform
    float oacc[10];
    #pragma unroll
    for (int c = 0; c < 10; c++) oacc[c] = b2[kh * 10 + c];   // uniform s_load

    float* myts = ts + (size_t)(kh * 64 + lane) * 20;

    for (int jt = 0; jt < 16; jt++) {
        __syncthreads();                   // prev tile's reads done before overwrite
        #pragma unroll
        for (int jj4 = 0; jj4 < 4; jj4++) {
            float4 p;
            #pragma unroll
            for (int q = 0; q < 4; q++) {
                int j = jt * 16 + jj4 * 4 + q;
                const float* w = wq + (size_t)j * IN_F;       // uniform -> s_load
                float a0 = 0.f, a1 = 0.f, a2 = 0.f, a3 = 0.f;
                #pragma unroll
                for (int i = 0; i < 8; i += 4) {
                    a0 = fmaf(h[i+0].x, w[(i+0)*4+0], a0);
                    a0 = fmaf(h[i+0].y, w[(i+0)*4+1], a0);
                    a0 = fmaf(h[i+0].z, w[(i+0)*4+2], a0);
                    a0 = fmaf(h[i+0].w, w[(i+0)*4+3], a0);
                    a1 = fmaf(h[i+1].x, w[(i+1)*4+0], a1);
                    a1 = fmaf(h[i+1].y, w[(i+1)*4+1], a1);
                    a1 = fmaf(h[i+1].z, w[(i+1)*4+2], a1);
                    a1 = fmaf(h[i+1].w, w[(i+1)*4+3], a1);
                    a2 = fmaf(h[i+2].x, w[(i+2)*4+0], a2);
                    a2 = fmaf(h[i+2].y, w[(i+2)*4+1], a2);
                    a2 = fmaf(h[i+2].z, w[(i+2)*4+2], a2);
                    a2 = fmaf(h[i+2].w, w[(i+2)*4+3], a2);
                    a3 = fmaf(h[i+3].x, w[(i+3)*4+0], a3);
                    a3 = fmaf(h[i+3].y, w[(i+3)*4+1], a3);
                    a3 = fmaf(h[i+3].z, w[(i+3)*4+2], a3);
                    a3 = fmaf(h[i+3].w, w[(i+3)*4+3], a3);
                }
                (&p.x)[q] = (a0 + a1) + (a2 + a3);
            }
            *((float4*)myts + jj4) = p;
        }
        __syncthreads();
        #pragma unroll
        for (int jj4 = 0; jj4 < 4; jj4++) {
            float4 u0 = *((const float4*)(ts + (size_t)(0 * 64 + lane) * 20) + jj4);
            float4 u1 = *((const float4*)(ts + (size_t)(1 * 64 + lane) * 20) + jj4);
            float4 u2 = *((const float4*)(ts + (size_t)(2 * 64 + lane) * 20) + jj4);
            float4 u3 = *((const float4*)(ts + (size_t)(3 * 64 + lane) * 20) + jj4);
            float4 v = f4add(f4add(u0, u1), f4add(u2, u3));
            int jb = jt * 16 + jj4 * 4;
            v.x = fmaxf(v.x + b1[jb + 0], 0.f);   // b1: uniform s_load
            v.y = fmaxf(v.y + b1[jb + 1], 0.f);
            v.z = fmaxf(v.z + b1[jb + 2], 0.f);
            v.w = fmaxf(v.w + b1[jb + 3], 0.f);
            #pragma unroll
            for (int q = 0; q < 4; q++) {
                float vv = (&v.x)[q];
                const float* w2r = W2 + (size_t)(jb + q) * CLS_F + kh * 10;  // uniform
                #pragma unroll
                for (int c = 0; c < 10; c++)
                    oacc[c] = fmaf(vv, w2r[c], oacc[c]);
            }
        }
    }

    float* op = out + (size_t)n * CLS_F + kh * 10;
    #pragma unroll
    for (int c = 0; c < 10; c++) op[c] = oacc[c];
}

// ---------------- launch ----------------

extern "C" void kernel_launch(void* const* d_in, const int* in_sizes, int n_in,
                              void* d_out, int out_size, void* d_ws, size_t ws_size,
                              hipStream_t stream) {
    const float* features = (const float*)d_in[0];
    const int*   src      = (const int*)d_in[1];
    const int*   dst      = (const int*)d_in[2];
    const float* W1       = (const float*)d_in[3];
    const float* b1       = (const float*)d_in[4];
    const float* W2       = (const float*)d_in[5];
    const float* b2       = (const float*)d_in[6];
    float*       out      = (float*)d_out;

    char* ws = (char*)d_ws;
    size_t off = 0;
    auto alloc = [&](size_t bytes) -> void* {
        void* p = ws + off;
        off += (bytes + 255) & ~(size_t)255;
        return p;
    };
    int*   counts = (int*)alloc((size_t)N_NODES * 4);
    int*   rowptr = (int*)alloc((size_t)N_NODES * 4);
    int*   cursor = (int*)alloc((size_t)N_NODES * 4);
    int*   bsum   = (int*)alloc(256 * 4);
    float* norm   = (float*)alloc((size_t)N_NODES * 4);
    float* norm2  = (float*)alloc((size_t)N_NODES * 4);
    float* W1t    = (float*)alloc((size_t)HID_F * IN_F * 4);
    int*   csr    = (int*)alloc((size_t)N_EDGES * 4);
    float* bufA   = (float*)alloc((size_t)N_NODES * IN_F * 4);
    float* bufB   = (float*)alloc((size_t)N_NODES * IN_F * 4);

    hipMemsetAsync(counts, 0, (size_t)N_NODES * 4, stream);

    int nb = (N_NODES + 255) / 256;   // 157
    k_count<<<(N_EDGES + 255) / 256, 256, 0, stream>>>(dst, counts);
    k_scan1<<<nb, 256, 0, stream>>>(counts, bsum);
    k_scan2<<<1, 64, 0, stream>>>(bsum, nb);
    k_scan3<<<nb, 256, 0, stream>>>(counts, bsum, rowptr, cursor, norm, norm2);
    k_fill<<<(N_EDGES + 255) / 256, 256, 0, stream>>>(src, dst, cursor, csr);
    k_w1t<<<(HID_F * IN_F + 255) / 256, 256, 0, stream>>>(W1, W1t);

    // g0 = features * norm  -> bufA
    k_pre<<<(N_NODES * (IN_F / 4) + 255) / 256, 256, 0, stream>>>(features, norm, bufA);
    // hop1: bufB = norm2[dst] * sum(g0[src])   (pre-scaled for hop2)
    k_hop<<<(N_NODES + 7) / 8, 256, 0, stream>>>(bufA, bufB, csr, rowptr, counts, norm2, 1);
    // hop2: bufA = sum(bufB[src])              (trailing norm folded into MLP)
    k_hop<<<(N_NODES + 7) / 8, 256, 0, stream>>>(bufB, bufA, csr, rowptr, counts, norm2, 0);

    k_mlp<<<N_NODES / 64, 256, 0, stream>>>(bufA, norm, W1t, b1, W2, b2, out);
}